// Round 1
// 496.010 us; speedup vs baseline: 1.1624x; 1.1624x over previous
//
#include <hip/hip_runtime.h>

typedef __attribute__((ext_vector_type(8))) short short8;
typedef __attribute__((ext_vector_type(4))) float float4_;

#define SDIM    137
#define HID     256
#define K0PAD   160     // state (137) padded to 5 k-blocks of 32
#define KAUG    416     // 256 (h) + 160 (state part)
#define MTILE   128     // rows per block (was 64): 1 block/CU, deep per-wave ILP
#define NROWT   (MTILE / 16)
#define NTHR    512     // 8 waves; each wave owns a 32-out-col strip

struct __attribute__((aligned(8))) U2 { unsigned x, y; };

__device__ __forceinline__ unsigned short f2bf(float f) {
  union { float f; unsigned int i; } v; v.f = f;
  return (unsigned short)((v.i + 0x8000u) >> 16);   // round-half-up
}
// pack two floats -> two bf16 in one dword: low16 = bf16(a), high16 = bf16(b)
__device__ __forceinline__ unsigned pack_bf16(float a, float b) {
  union { float f; unsigned u; } ua, ub; ua.f = a; ub.f = b;
  return __builtin_amdgcn_perm(ub.u + 0x8000u, ua.u + 0x8000u, 0x07060302u);
}
__device__ __forceinline__ float lo_bf(unsigned p) {
  union { unsigned u; float f; } v; v.u = p << 16; return v.f;
}
__device__ __forceinline__ float hi_bf(unsigned p) {
  union { unsigned u; float f; } v; v.u = p & 0xFFFF0000u; return v.f;
}
// tanh(x) = 1 - 2/(e^{2x}+1); rcp handles +-inf -> saturates to +-1.
__device__ __forceinline__ float fast_tanh(float x) {
  float e = __expf(2.f * x);
  float r = __builtin_amdgcn_rcpf(e + 1.f);
  return __builtin_fmaf(-2.f, r, 1.f);
}
// LDS index (in ushorts) for activation tiles: row stride 256 els, 16B-chunk XOR swizzle.
__device__ __forceinline__ int sidx(int row, int col) {
  return row * 256 + ((((col >> 3) ^ (row & 31)) << 3) | (col & 7));
}

// acc[2][NROWT] += W(A-operand, global [M][K] row-major) @ X(B-operand, LDS swizzled)
// Wave owns out-col strip [colbase, colbase+32).
//   A: lane reads W row m = colbase+mt*16+(lane&15), k = kb*32+(lane>>4)*8 ..+7
//   B: lane reads X row n = nt*16+(lane&15), same k window (16B chunk kb*4+q)
// C/D: lane holds (out-col = colbase+mt*16+q*4+i, batch-row = nt*16+(lane&15))
// ALL W-strip loads are hoisted ahead of the K-loop: 2*NK global loads issue
// back-to-back (addresses differ only by imm-foldable k offsets), so their L2
// latency amortizes over the whole K-loop instead of stalling each kb step.
template<int NK, int LDB, int BOFF>
__device__ __forceinline__ void mma_wact(const unsigned short* __restrict__ X,
                                         const unsigned short* __restrict__ W,
                                         float4_ (&acc)[2][NROWT], int lane, int colbase)
{
  const int q  = lane >> 4;
  const int rm = lane & 15;
  short8 wa[NK][2];
  #pragma unroll
  for (int kb = 0; kb < NK; ++kb)
    #pragma unroll
    for (int mt = 0; mt < 2; ++mt) {
      int m = colbase + mt * 16 + rm;
      wa[kb][mt] = *(const short8*)(W + (size_t)m * LDB + BOFF + kb * 32 + q * 8);
    }
  #pragma unroll
  for (int kb = 0; kb < NK; ++kb) {
    short8 xb[NROWT];
    #pragma unroll
    for (int nt = 0; nt < NROWT; ++nt) {
      int row = nt * 16 + rm;
      int c   = kb * 4 + q;
      xb[nt] = *(const short8*)(X + row * 256 + (((c ^ (row & 31)) << 3)));
    }
    #pragma unroll
    for (int mt = 0; mt < 2; ++mt)
      #pragma unroll
      for (int nt = 0; nt < NROWT; ++nt)
        acc[mt][nt] = __builtin_amdgcn_mfma_f32_16x16x32_bf16(wa[kb][mt], xb[nt], acc[mt][nt], 0, 0, 0);
  }
}

// ---------------- prep kernels (tiny, once per launch) ----------------

// grid 256 x 64: block n converts W0 row n, folds time features into bias.
__global__ void prep_w0(const float* __restrict__ t,
                        const float* __restrict__ W0,
                        const float* __restrict__ b0,
                        unsigned short* __restrict__ W0p,
                        float* __restrict__ b0p)
{
  int n = blockIdx.x;
  int tt = threadIdx.x;
  for (int k = tt; k < K0PAD; k += 64)
    W0p[n * K0PAD + k] = (k < SDIM) ? f2bf(W0[n * 139 + k]) : (unsigned short)0;
  if (tt == 0) {
    float tv  = t[0];
    float ang = tv * (6.2831853071795864f / 24.0f);
    float sv = __sinf(ang), cv = __cosf(ang);
    b0p[n] = b0[n] + W0[n * 139 + 137] * sv + W0[n * 139 + 138] * cv;
  }
}

// grid 256 x 128: default fill of Waug (Wout block + zeros) and baug (bout / 0).
// The attention-derived patches are overwritten by prep_ta (stream-ordered after).
__global__ void prep_fill(const float* __restrict__ Wout,
                          const float* __restrict__ bout,
                          unsigned short* __restrict__ Waug,
                          float* __restrict__ baug)
{
  int n = blockIdx.x;
  int tt = threadIdx.x;
  if (tt < KAUG / 4) {
    int k0 = tt * 4;
    U2 p;
    if (k0 < 256 && n < SDIM) {
      float4_ v = *(const float4_*)(Wout + (size_t)n * 256 + k0);
      p.x = pack_bf16(v[0], v[1]); p.y = pack_bf16(v[2], v[3]);
    } else {
      p.x = 0u; p.y = 0u;
    }
    *(U2*)(Waug + (size_t)n * KAUG + k0) = p;
  } else if (tt == KAUG / 4) {
    baug[n] = (n < SDIM) ? bout[n] : 0.f;
  }
}

// grid 129 x 128. Blocks 0..127: row n of the ta patch -- thread s computes the
// 128-deep dot fully in parallel (was: 1-wave blocks doing serial dots).
// Block 128: the 8x8 lm patch + lm bias. Biases are += on top of prep_fill.
__global__ void prep_ta(const float* __restrict__ ta_in_w,
                        const float* __restrict__ ta_in_b,
                        const float* __restrict__ ta_out_w,
                        const float* __restrict__ ta_out_b,
                        const float* __restrict__ lm_in_w,
                        const float* __restrict__ lm_in_b,
                        const float* __restrict__ lm_out_w,
                        const float* __restrict__ lm_out_b,
                        unsigned short* __restrict__ Waug,
                        float* __restrict__ baug)
{
  __shared__ float red[128];
  int blk = blockIdx.x;
  int tt  = threadIdx.x;
  if (blk < 128) {
    int n = blk, s = tt;
    float dot = 0.f;
    #pragma unroll 8
    for (int r = 0; r < 128; ++r)
      dot += ta_out_w[n * 128 + r] * ta_in_w[(256 + r) * 128 + s];
    float v = 0.1f * (dot - (s == n ? 1.f : 0.f));
    Waug[(size_t)n * KAUG + 256 + s] = f2bf(v);

    red[tt] = ta_out_w[n * 128 + tt] * ta_in_b[256 + tt];
    __syncthreads();
    if (tt < 64) {
      float p = red[tt] + red[tt + 64];
      for (int off = 32; off; off >>= 1) p += __shfl_down(p, off);
      if (tt == 0) baug[n] += 0.1f * (p + ta_out_b[n]);
    }
  } else {
    if (tt < 64) {
      int a = tt >> 3, b = tt & 7;
      float dot = 0.f;
      #pragma unroll
      for (int r = 0; r < 8; ++r)
        dot += lm_out_w[a * 8 + r] * lm_in_w[(16 + r) * 8 + b];
      Waug[(size_t)(128 + a) * KAUG + 384 + b] = f2bf(0.1f * (dot - (a == b ? 1.f : 0.f)));
    } else if (tt < 72) {
      int a = tt - 64;
      float dot = 0.f;
      #pragma unroll
      for (int r = 0; r < 8; ++r)
        dot += lm_out_w[a * 8 + r] * lm_in_b[16 + r];
      baug[128 + a] += 0.1f * (dot + lm_out_b[a]);
    }
  }
}

// grid 512 x 256: both residual weight blocks, 4 floats -> 4 bf16 per thread.
__global__ void prep_blk2(const float* __restrict__ s1, const float* __restrict__ s2,
                          unsigned short* __restrict__ d1, unsigned short* __restrict__ d2)
{
  int i = (blockIdx.x * 256 + threadIdx.x) * 4;
  const float* s; unsigned short* d;
  if (i < 262144) { s = s1 + i;          d = d1 + i; }
  else            { s = s2 + i - 262144; d = d2 + i - 262144; }
  float4_ v = *(const float4_*)s;
  U2 p; p.x = pack_bf16(v[0], v[1]); p.y = pack_bf16(v[2], v[3]);
  *(U2*)d = p;
}

// ---------------- fused main kernel ----------------
// 512 thr / 8 waves, 128-row tile, 128 KiB LDS arena -> 1 block/CU (2 waves/EU).
// min-waves/EU = 2 -> up to 256 VGPRs: room for hoisted W strips + acc[2][8].

__global__ __launch_bounds__(NTHR, 2)
void fused_odefunc(
    const float* __restrict__ state,
    const unsigned short* __restrict__ W0p,
    const float* __restrict__ b0p,
    const unsigned short* __restrict__ blkW1,
    const float* __restrict__ blkb1,
    const unsigned short* __restrict__ blkW2,
    const float* __restrict__ blkb2,
    const unsigned short* __restrict__ Waug,
    const float* __restrict__ baug,
    float* __restrict__ out)
{
  __shared__ __align__(16) unsigned short ARENA[2 * MTILE * 256];   // 128 KiB
  unsigned short* H = ARENA;                 // h tile (persists across blocks)
  unsigned short* G = ARENA + MTILE * 256;   // state / g tile (ping)
  float*          T = (float*)ARENA;         // final fp32 out tile 128x140 (reuse)

  const int tid  = threadIdx.x;
  const int lane = tid & 63;
  const int wave = tid >> 6;               // 0..7
  const int q    = lane >> 4;
  const int rm   = lane & 15;
  const int cb   = wave * 32;              // this wave's out-col base
  const int row0 = blockIdx.x * MTILE;

  // ---- stage state tile (fp32 -> bf16, packed b64) -> G
  #pragma unroll 2
  for (int qd = tid; qd < MTILE * (K0PAD / 4); qd += NTHR) {   // 5120 quads
    int m  = qd / (K0PAD / 4);
    int k0 = (qd - m * (K0PAD / 4)) * 4;
    const float* sp = state + (size_t)(row0 + m) * SDIM + k0;
    float f0 = (k0     < SDIM) ? sp[0] : 0.f;
    float f1 = (k0 + 1 < SDIM) ? sp[1] : 0.f;
    float f2 = (k0 + 2 < SDIM) ? sp[2] : 0.f;
    float f3 = (k0 + 3 < SDIM) ? sp[3] : 0.f;
    U2 p; p.x = pack_bf16(f0, f1); p.y = pack_bf16(f2, f3);
    *(U2*)(&G[sidx(m, k0)]) = p;
  }
  __syncthreads();

  // ---- layer 0: h = relu(W0p @ state^T) -> H
  {
    float4_ acc[2][NROWT];
    #pragma unroll
    for (int mt = 0; mt < 2; ++mt)
      #pragma unroll
      for (int nt = 0; nt < NROWT; ++nt) acc[mt][nt] = (float4_){0.f, 0.f, 0.f, 0.f};
    mma_wact<K0PAD / 32, K0PAD, 0>(G, W0p, acc, lane, cb);
    #pragma unroll
    for (int mt = 0; mt < 2; ++mt) {
      int col0 = cb + mt * 16 + q * 4;
      float4_ bias = *(const float4_*)(b0p + col0);
      #pragma unroll
      for (int nt = 0; nt < NROWT; ++nt) {
        int row = nt * 16 + rm;
        float v0 = fmaxf(acc[mt][nt][0] + bias[0], 0.f);
        float v1 = fmaxf(acc[mt][nt][1] + bias[1], 0.f);
        float v2 = fmaxf(acc[mt][nt][2] + bias[2], 0.f);
        float v3 = fmaxf(acc[mt][nt][3] + bias[3], 0.f);
        U2 p; p.x = pack_bf16(v0, v1); p.y = pack_bf16(v2, v3);
        *(U2*)(&H[sidx(row, col0)]) = p;
      }
    }
  }
  __syncthreads();

  // ---- 4 residual blocks: g = tanh(W1@h^T+b1) -> G;  h = tanh(h + W2@g^T+b2) in H
  for (int blk = 0; blk < 4; ++blk) {
    const unsigned short* W1 = blkW1 + (size_t)blk * 65536;
    const float*          b1 = blkb1 + blk * 256;
    const unsigned short* W2 = blkW2 + (size_t)blk * 65536;
    const float*          b2 = blkb2 + blk * 256;

    float4_ acc[2][NROWT];
    #pragma unroll
    for (int mt = 0; mt < 2; ++mt)
      #pragma unroll
      for (int nt = 0; nt < NROWT; ++nt) acc[mt][nt] = (float4_){0.f, 0.f, 0.f, 0.f};
    mma_wact<8, 256, 0>(H, W1, acc, lane, cb);
    #pragma unroll
    for (int mt = 0; mt < 2; ++mt) {
      int col0 = cb + mt * 16 + q * 4;
      float4_ bias = *(const float4_*)(b1 + col0);
      #pragma unroll
      for (int nt = 0; nt < NROWT; ++nt) {
        int row = nt * 16 + rm;
        float v0 = fast_tanh(acc[mt][nt][0] + bias[0]);
        float v1 = fast_tanh(acc[mt][nt][1] + bias[1]);
        float v2 = fast_tanh(acc[mt][nt][2] + bias[2]);
        float v3 = fast_tanh(acc[mt][nt][3] + bias[3]);
        U2 p; p.x = pack_bf16(v0, v1); p.y = pack_bf16(v2, v3);
        *(U2*)(&G[sidx(row, col0)]) = p;
      }
    }
    __syncthreads();

    #pragma unroll
    for (int mt = 0; mt < 2; ++mt)
      #pragma unroll
      for (int nt = 0; nt < NROWT; ++nt) acc[mt][nt] = (float4_){0.f, 0.f, 0.f, 0.f};
    mma_wact<8, 256, 0>(G, W2, acc, lane, cb);
    #pragma unroll
    for (int mt = 0; mt < 2; ++mt) {
      int col0 = cb + mt * 16 + q * 4;
      float4_ bias = *(const float4_*)(b2 + col0);
      #pragma unroll
      for (int nt = 0; nt < NROWT; ++nt) {
        int row = nt * 16 + rm;
        int idx = sidx(row, col0);
        U2 old = *(const U2*)(&H[idx]);                 // lane-owned slots
        float v0 = fast_tanh(lo_bf(old.x) + acc[mt][nt][0] + bias[0]);
        float v1 = fast_tanh(hi_bf(old.x) + acc[mt][nt][1] + bias[1]);
        float v2 = fast_tanh(lo_bf(old.y) + acc[mt][nt][2] + bias[2]);
        float v3 = fast_tanh(hi_bf(old.y) + acc[mt][nt][3] + bias[3]);
        U2 p; p.x = pack_bf16(v0, v1); p.y = pack_bf16(v2, v3);
        *(U2*)(&H[idx]) = p;
      }
    }
    __syncthreads();
  }

  // ---- final: out = Waug @ [h; state]^T + baug  (only out-cols < 160 needed)
  // restage state -> G (G dead since last GEMM2; safe before barrier)
  #pragma unroll 2
  for (int qd = tid; qd < MTILE * (K0PAD / 4); qd += NTHR) {
    int m  = qd / (K0PAD / 4);
    int k0 = (qd - m * (K0PAD / 4)) * 4;
    const float* sp = state + (size_t)(row0 + m) * SDIM + k0;
    float f0 = (k0     < SDIM) ? sp[0] : 0.f;
    float f1 = (k0 + 1 < SDIM) ? sp[1] : 0.f;
    float f2 = (k0 + 2 < SDIM) ? sp[2] : 0.f;
    float f3 = (k0 + 3 < SDIM) ? sp[3] : 0.f;
    U2 p; p.x = pack_bf16(f0, f1); p.y = pack_bf16(f2, f3);
    *(U2*)(&G[sidx(m, k0)]) = p;
  }

  float4_ acc[2][NROWT];
  #pragma unroll
  for (int mt = 0; mt < 2; ++mt)
    #pragma unroll
    for (int nt = 0; nt < NROWT; ++nt) acc[mt][nt] = (float4_){0.f, 0.f, 0.f, 0.f};
  if (cb < 160)
    mma_wact<8, KAUG, 0>(H, Waug, acc, lane, cb);        // h part (k 0..255)
  __syncthreads();                                       // G staged + H reads done
  if (cb < 160)
    mma_wact<5, KAUG, 256>(G, Waug, acc, lane, cb);      // state part (k 256..415)
  __syncthreads();                                       // all arena reads done
  if (cb < 160) {
    #pragma unroll
    for (int mt = 0; mt < 2; ++mt) {
      int col0 = cb + mt * 16 + q * 4;
      if (col0 <= 136) {
        float4_ bias = *(const float4_*)(baug + col0);
        #pragma unroll
        for (int nt = 0; nt < NROWT; ++nt) {
          int row = nt * 16 + rm;
          float4_ v;
          v[0] = acc[mt][nt][0] + bias[0];
          v[1] = acc[mt][nt][1] + bias[1];
          v[2] = acc[mt][nt][2] + bias[2];
          v[3] = acc[mt][nt][3] + bias[3];
          *(float4_*)(T + row * 140 + col0) = v;        // fp32 tile, stride 140
        }
      }
    }
  }
  __syncthreads();

  // ---- fully coalesced linear store: 128*137 contiguous floats (no div in loop)
  float* obase = out + (size_t)row0 * SDIM;
  int r = tid / SDIM;                 // 0..3
  int c = tid - r * SDIM;
  #pragma unroll 1
  for (int idx = tid; idx < MTILE * SDIM; idx += NTHR) {
    obase[idx] = T[r * 140 + c];
    c += NTHR - 3 * SDIM;             // +101  (512 = 3*137 + 101)
    r += 3;
    if (c >= SDIM) { c -= SDIM; r += 1; }
  }
}

extern "C" void kernel_launch(void* const* d_in, const int* in_sizes, int n_in,
                              void* d_out, int out_size, void* d_ws, size_t ws_size,
                              hipStream_t stream) {
  const float* t        = (const float*)d_in[0];
  const float* state    = (const float*)d_in[1];
  const float* W0       = (const float*)d_in[2];
  const float* b0       = (const float*)d_in[3];
  const float* blkW1    = (const float*)d_in[4];
  const float* blkb1    = (const float*)d_in[5];
  const float* blkW2    = (const float*)d_in[6];
  const float* blkb2    = (const float*)d_in[7];
  const float* Wout     = (const float*)d_in[8];
  const float* bout     = (const float*)d_in[9];
  const float* lm_in_w  = (const float*)d_in[10];
  const float* lm_in_b  = (const float*)d_in[11];
  const float* lm_out_w = (const float*)d_in[12];
  const float* lm_out_b = (const float*)d_in[13];
  const float* ta_in_w  = (const float*)d_in[14];
  const float* ta_in_b  = (const float*)d_in[15];
  const float* ta_out_w = (const float*)d_in[16];
  const float* ta_out_b = (const float*)d_in[17];

  char* ws = (char*)d_ws;
  unsigned short* W0p   = (unsigned short*)ws;                   // 256*160*2   = 81920
  float*          b0p   = (float*)(ws + 81920);                  // 1024
  unsigned short* Waug  = (unsigned short*)(ws + 82944);         // 256*416*2   = 212992
  float*          baug  = (float*)(ws + 295936);                 // 1024
  unsigned short* W1b   = (unsigned short*)(ws + 296960);        // 4*256*256*2 = 524288
  unsigned short* W2b   = (unsigned short*)(ws + 821248);        // 524288  (total ~1.31 MB)

  prep_w0<<<256, 64, 0, stream>>>(t, W0, b0, W0p, b0p);
  prep_fill<<<256, 128, 0, stream>>>(Wout, bout, Waug, baug);
  prep_ta<<<129, 128, 0, stream>>>(ta_in_w, ta_in_b, ta_out_w, ta_out_b,
                                   lm_in_w, lm_in_b, lm_out_w, lm_out_b, Waug, baug);
  prep_blk2<<<512, 256, 0, stream>>>(blkW1, blkW2, W1b, W2b);

  int batch = in_sizes[1] / SDIM;               // 131072
  fused_odefunc<<<batch / MTILE, NTHR, 0, stream>>>(
      state, W0p, b0p, W1b, blkb1, W2b, blkb2, Waug, baug,
      (float*)d_out);
}

// Round 2
// 456.571 us; speedup vs baseline: 1.2628x; 1.0864x over previous
//
#include <hip/hip_runtime.h>

typedef __attribute__((ext_vector_type(8))) short short8;
typedef __attribute__((ext_vector_type(4))) float float4_;

#define SDIM    137
#define HID     256
#define K0PAD   160     // state (137) padded to 5 k-blocks of 32
#define KAUG    416     // 256 (h) + 160 (state part)
#define MTILE   128     // rows per block: 1 block/CU, deep per-wave ILP
#define NROWT   (MTILE / 16)
#define NTHR    512     // 8 waves; each wave owns a 32-out-col strip

// Activations are stored pre-scaled by SCLF = 2*log2(e): tanh(x) = 1-2/(exp2(s*x)+1),
// and s*W*h = W*(s*h), so W1/W2 stay unscaled; s folds into W0p/b0p (prep), biases
// (runtime, once per GEMM), and 1/s into Waug's h-half (prep).
#define SCLF 2.8853900817779268f
#define ISCL 0.34657359027997264f

struct __attribute__((aligned(8))) U2 { unsigned x, y; };

__device__ __forceinline__ unsigned short f2bf(float f) {
  union { float f; unsigned int i; } v; v.f = f;
  return (unsigned short)((v.i + 0x8000u) >> 16);   // round-half-up
}
// pack two floats -> two bf16 in one dword (prep kernels; round-half-up)
__device__ __forceinline__ unsigned pack_bf16(float a, float b) {
  union { float f; unsigned u; } ua, ub; ua.f = a; ub.f = b;
  return __builtin_amdgcn_perm(ub.u + 0x8000u, ua.u + 0x8000u, 0x07060302u);
}
// hot-path pack: single HW instr, RNE rounding. low16 = bf16(a), high16 = bf16(b)
__device__ __forceinline__ unsigned cvt_pk(float a, float b) {
  unsigned r;
  asm("v_cvt_pk_bf16_f32 %0, %1, %2" : "=v"(r) : "v"(a), "v"(b));
  return r;
}
__device__ __forceinline__ float lo_bf(unsigned p) {
  union { unsigned u; float f; } v; v.u = p << 16; return v.f;
}
__device__ __forceinline__ float hi_bf(unsigned p) {
  union { unsigned u; float f; } v; v.u = p & 0xFFFF0000u; return v.f;
}
// y is pre-scaled by 2*log2(e): returns s*tanh(x) where y = s*x.
__device__ __forceinline__ float stanh(float y) {
#if __has_builtin(__builtin_amdgcn_exp2f)
  float e = __builtin_amdgcn_exp2f(y);
#else
  float e = __expf(y * 0.6931471805599453f);
#endif
  float r = __builtin_amdgcn_rcpf(e + 1.f);
  return __builtin_fmaf(-2.f * SCLF, r, SCLF);
}
// LDS index (in ushorts) for activation tiles: row stride 256 els, 16B-chunk XOR swizzle.
__device__ __forceinline__ int sidx(int row, int col) {
  return row * 256 + ((((col >> 3) ^ (row & 31)) << 3) | (col & 7));
}
// B-fragment read: row, 16B-chunk index c
__device__ __forceinline__ short8 ld_x(const unsigned short* __restrict__ X, int row, int c) {
  return *(const short8*)(X + row * 256 + (((c ^ (row & 31)) << 3)));
}

// hoist the wave's full W strip (32 cols x NK*32 k) into registers: 2*NK x 16B loads
template<int NK, int LDB, int BOFF>
__device__ __forceinline__ void load_wa(const unsigned short* __restrict__ W,
                                        short8 (&wa)[NK][2], int colbase, int rm, int q)
{
  #pragma unroll
  for (int kb = 0; kb < NK; ++kb)
    #pragma unroll
    for (int mt = 0; mt < 2; ++mt)
      wa[kb][mt] = *(const short8*)(W + (size_t)(colbase + mt * 16 + rm) * LDB
                                      + BOFF + kb * 32 + q * 8);
}

// nt-outer fused GEMM: for each 16-row tile, issue ds_reads + MFMA chain, then run
// the (pure-VALU) epilogue of the PREVIOUS row tile -- no data dependency, so the
// tanh/pack work schedules into the MFMA shadow instead of serializing after it.
template<int NK, class EPI>
__device__ __forceinline__ void gemm_f(const unsigned short* __restrict__ X,
                                       const short8 (&wa)[NK][2],
                                       int rm, int q, EPI epi)
{
  float4_ a[NROWT][2];
  #pragma unroll
  for (int nt = 0; nt < NROWT; ++nt) {
    short8 xb[NK];
    #pragma unroll
    for (int kb = 0; kb < NK; ++kb) xb[kb] = ld_x(X, nt * 16 + rm, kb * 4 + q);
    a[nt][0] = (float4_){0.f, 0.f, 0.f, 0.f};
    a[nt][1] = (float4_){0.f, 0.f, 0.f, 0.f};
    #pragma unroll
    for (int kb = 0; kb < NK; ++kb) {
      a[nt][0] = __builtin_amdgcn_mfma_f32_16x16x32_bf16(wa[kb][0], xb[kb], a[nt][0], 0, 0, 0);
      a[nt][1] = __builtin_amdgcn_mfma_f32_16x16x32_bf16(wa[kb][1], xb[kb], a[nt][1], 0, 0, 0);
    }
    if (nt > 0) epi(nt - 1, a[nt - 1]);
  }
  epi(NROWT - 1, a[NROWT - 1]);
}

// legacy kb-outer path (final GEMM: two accumulation passes over H then G)
template<int NK, int LDB, int BOFF>
__device__ __forceinline__ void mma_wact(const unsigned short* __restrict__ X,
                                         const unsigned short* __restrict__ W,
                                         float4_ (&acc)[2][NROWT], int lane, int colbase)
{
  const int q  = lane >> 4;
  const int rm = lane & 15;
  short8 wa[NK][2];
  load_wa<NK, LDB, BOFF>(W, wa, colbase, rm, q);
  #pragma unroll
  for (int kb = 0; kb < NK; ++kb) {
    short8 xb[NROWT];
    #pragma unroll
    for (int nt = 0; nt < NROWT; ++nt)
      xb[nt] = ld_x(X, nt * 16 + rm, kb * 4 + q);
    #pragma unroll
    for (int mt = 0; mt < 2; ++mt)
      #pragma unroll
      for (int nt = 0; nt < NROWT; ++nt)
        acc[mt][nt] = __builtin_amdgcn_mfma_f32_16x16x32_bf16(wa[kb][mt], xb[nt], acc[mt][nt], 0, 0, 0);
  }
}

// ---------------- prep kernels (tiny, once per launch) ----------------

// grid 256 x 64: block n converts W0 row n (scaled by SCLF), folds time into bias.
__global__ void prep_w0(const float* __restrict__ t,
                        const float* __restrict__ W0,
                        const float* __restrict__ b0,
                        unsigned short* __restrict__ W0p,
                        float* __restrict__ b0p)
{
  int n = blockIdx.x;
  int tt = threadIdx.x;
  for (int k = tt; k < K0PAD; k += 64)
    W0p[n * K0PAD + k] = (k < SDIM) ? f2bf(W0[n * 139 + k] * SCLF) : (unsigned short)0;
  if (tt == 0) {
    float tv  = t[0];
    float ang = tv * (6.2831853071795864f / 24.0f);
    float sv = __sinf(ang), cv = __cosf(ang);
    b0p[n] = SCLF * (b0[n] + W0[n * 139 + 137] * sv + W0[n * 139 + 138] * cv);
  }
}

// grid 256 x 128: default fill of Waug (Wout/SCLF on the h-half + zeros) and baug.
__global__ void prep_fill(const float* __restrict__ Wout,
                          const float* __restrict__ bout,
                          unsigned short* __restrict__ Waug,
                          float* __restrict__ baug)
{
  int n = blockIdx.x;
  int tt = threadIdx.x;
  if (tt < KAUG / 4) {
    int k0 = tt * 4;
    U2 p;
    if (k0 < 256 && n < SDIM) {
      float4_ v = *(const float4_*)(Wout + (size_t)n * 256 + k0);
      p.x = pack_bf16(v[0] * ISCL, v[1] * ISCL); p.y = pack_bf16(v[2] * ISCL, v[3] * ISCL);
    } else {
      p.x = 0u; p.y = 0u;
    }
    *(U2*)(Waug + (size_t)n * KAUG + k0) = p;
  } else if (tt == KAUG / 4) {
    baug[n] = (n < SDIM) ? bout[n] : 0.f;
  }
}

// grid 129 x 128. Blocks 0..127: ta patch row n, thread s does the 128-deep dot.
// Block 128: 8x8 lm patch + lm bias. Biases += on top of prep_fill. (state-half:
// NOT scaled -- the state operand is staged unscaled.)
__global__ void prep_ta(const float* __restrict__ ta_in_w,
                        const float* __restrict__ ta_in_b,
                        const float* __restrict__ ta_out_w,
                        const float* __restrict__ ta_out_b,
                        const float* __restrict__ lm_in_w,
                        const float* __restrict__ lm_in_b,
                        const float* __restrict__ lm_out_w,
                        const float* __restrict__ lm_out_b,
                        unsigned short* __restrict__ Waug,
                        float* __restrict__ baug)
{
  __shared__ float red[128];
  int blk = blockIdx.x;
  int tt  = threadIdx.x;
  if (blk < 128) {
    int n = blk, s = tt;
    float dot = 0.f;
    #pragma unroll 8
    for (int r = 0; r < 128; ++r)
      dot += ta_out_w[n * 128 + r] * ta_in_w[(256 + r) * 128 + s];
    float v = 0.1f * (dot - (s == n ? 1.f : 0.f));
    Waug[(size_t)n * KAUG + 256 + s] = f2bf(v);

    red[tt] = ta_out_w[n * 128 + tt] * ta_in_b[256 + tt];
    __syncthreads();
    if (tt < 64) {
      float p = red[tt] + red[tt + 64];
      for (int off = 32; off; off >>= 1) p += __shfl_down(p, off);
      if (tt == 0) baug[n] += 0.1f * (p + ta_out_b[n]);
    }
  } else {
    if (tt < 64) {
      int a = tt >> 3, b = tt & 7;
      float dot = 0.f;
      #pragma unroll
      for (int r = 0; r < 8; ++r)
        dot += lm_out_w[a * 8 + r] * lm_in_w[(16 + r) * 8 + b];
      Waug[(size_t)(128 + a) * KAUG + 384 + b] = f2bf(0.1f * (dot - (a == b ? 1.f : 0.f)));
    } else if (tt < 72) {
      int a = tt - 64;
      float dot = 0.f;
      #pragma unroll
      for (int r = 0; r < 8; ++r)
        dot += lm_out_w[a * 8 + r] * lm_in_b[16 + r];
      baug[128 + a] += 0.1f * (dot + lm_out_b[a]);
    }
  }
}

// grid 512 x 256: both residual weight blocks, 4 floats -> 4 bf16 per thread.
__global__ void prep_blk2(const float* __restrict__ s1, const float* __restrict__ s2,
                          unsigned short* __restrict__ d1, unsigned short* __restrict__ d2)
{
  int i = (blockIdx.x * 256 + threadIdx.x) * 4;
  const float* s; unsigned short* d;
  if (i < 262144) { s = s1 + i;          d = d1 + i; }
  else            { s = s2 + i - 262144; d = d2 + i - 262144; }
  float4_ v = *(const float4_*)s;
  U2 p; p.x = pack_bf16(v[0], v[1]); p.y = pack_bf16(v[2], v[3]);
  *(U2*)d = p;
}

// ---------------- fused main kernel ----------------
// 512 thr / 8 waves, 128-row tile, 128 KiB LDS arena -> 1 block/CU (2 waves/EU).
// waves_per_eu(2,2) forces the compiler to budget for exactly 2 waves/EU (<=256 VGPR)
// so the wa[8][2] hoist (64 VGPRs) actually survives register allocation.

__global__ __launch_bounds__(NTHR, 2)
__attribute__((amdgpu_waves_per_eu(2, 2)))
void fused_odefunc(
    const float* __restrict__ state,
    const unsigned short* __restrict__ W0p,
    const float* __restrict__ b0p,
    const unsigned short* __restrict__ blkW1,
    const float* __restrict__ blkb1,
    const unsigned short* __restrict__ blkW2,
    const float* __restrict__ blkb2,
    const unsigned short* __restrict__ Waug,
    const float* __restrict__ baug,
    float* __restrict__ out)
{
  __shared__ __align__(16) unsigned short ARENA[2 * MTILE * 256];   // 128 KiB
  unsigned short* H = ARENA;                 // h tile (persists across blocks)
  unsigned short* G = ARENA + MTILE * 256;   // state / g tile (ping)
  float*          T = (float*)ARENA;         // final fp32 out tile 128x140 (reuse)

  const int tid  = threadIdx.x;
  const int lane = tid & 63;
  const int wave = tid >> 6;               // 0..7
  const int q    = lane >> 4;
  const int rm   = lane & 15;
  const int cb   = wave * 32;              // this wave's out-col base
  const int row0 = blockIdx.x * MTILE;

  // ---- stage state tile (fp32 -> bf16, packed b64) -> G
  #pragma unroll 2
  for (int qd = tid; qd < MTILE * (K0PAD / 4); qd += NTHR) {   // 5120 quads
    int m  = qd / (K0PAD / 4);
    int k0 = (qd - m * (K0PAD / 4)) * 4;
    const float* sp = state + (size_t)(row0 + m) * SDIM + k0;
    float f0 = (k0     < SDIM) ? sp[0] : 0.f;
    float f1 = (k0 + 1 < SDIM) ? sp[1] : 0.f;
    float f2 = (k0 + 2 < SDIM) ? sp[2] : 0.f;
    float f3 = (k0 + 3 < SDIM) ? sp[3] : 0.f;
    U2 p; p.x = cvt_pk(f0, f1); p.y = cvt_pk(f2, f3);
    *(U2*)(&G[sidx(m, k0)]) = p;
  }
  __syncthreads();

  // ---- layer 0: h' = relu(W0p @ state^T) -> H   (W0p pre-scaled by SCLF)
  {
    short8 wa[K0PAD / 32][2];
    load_wa<K0PAD / 32, K0PAD, 0>(W0p, wa, cb, rm, q);
    float4_ bias[2];
    #pragma unroll
    for (int mt = 0; mt < 2; ++mt) bias[mt] = *(const float4_*)(b0p + cb + mt * 16 + q * 4);
    gemm_f<K0PAD / 32>(G, wa, rm, q, [&](int nt, float4_ (&a2)[2]) {
      int row = nt * 16 + rm;
      #pragma unroll
      for (int mt = 0; mt < 2; ++mt) {
        int col0 = cb + mt * 16 + q * 4;
        float v0 = fmaxf(a2[mt][0] + bias[mt][0], 0.f);
        float v1 = fmaxf(a2[mt][1] + bias[mt][1], 0.f);
        float v2 = fmaxf(a2[mt][2] + bias[mt][2], 0.f);
        float v3 = fmaxf(a2[mt][3] + bias[mt][3], 0.f);
        U2 p; p.x = cvt_pk(v0, v1); p.y = cvt_pk(v2, v3);
        *(U2*)(&H[sidx(row, col0)]) = p;
      }
    });
  }
  __syncthreads();

  // ---- 4 residual blocks: g' = stanh(W1@h') -> G;  h' = stanh(h' + W2@g') in H
  for (int blk = 0; blk < 4; ++blk) {
    const unsigned short* W1 = blkW1 + (size_t)blk * 65536;
    const float*          b1 = blkb1 + blk * 256;
    const unsigned short* W2 = blkW2 + (size_t)blk * 65536;
    const float*          b2 = blkb2 + blk * 256;

    {
      short8 wa[8][2];
      load_wa<8, 256, 0>(W1, wa, cb, rm, q);
      float4_ bb[2];
      #pragma unroll
      for (int mt = 0; mt < 2; ++mt) {
        float4_ t4 = *(const float4_*)(b1 + cb + mt * 16 + q * 4);
        bb[mt][0] = t4[0] * SCLF; bb[mt][1] = t4[1] * SCLF;
        bb[mt][2] = t4[2] * SCLF; bb[mt][3] = t4[3] * SCLF;
      }
      gemm_f<8>(H, wa, rm, q, [&](int nt, float4_ (&a2)[2]) {
        int row = nt * 16 + rm;
        #pragma unroll
        for (int mt = 0; mt < 2; ++mt) {
          int col0 = cb + mt * 16 + q * 4;
          float g0 = stanh(a2[mt][0] + bb[mt][0]);
          float g1 = stanh(a2[mt][1] + bb[mt][1]);
          float g2 = stanh(a2[mt][2] + bb[mt][2]);
          float g3 = stanh(a2[mt][3] + bb[mt][3]);
          U2 p; p.x = cvt_pk(g0, g1); p.y = cvt_pk(g2, g3);
          *(U2*)(&G[sidx(row, col0)]) = p;
        }
      });
    }
    __syncthreads();

    {
      short8 wa[8][2];
      load_wa<8, 256, 0>(W2, wa, cb, rm, q);
      float4_ bb[2];
      #pragma unroll
      for (int mt = 0; mt < 2; ++mt) {
        float4_ t4 = *(const float4_*)(b2 + cb + mt * 16 + q * 4);
        bb[mt][0] = t4[0] * SCLF; bb[mt][1] = t4[1] * SCLF;
        bb[mt][2] = t4[2] * SCLF; bb[mt][3] = t4[3] * SCLF;
      }
      gemm_f<8>(G, wa, rm, q, [&](int nt, float4_ (&a2)[2]) {
        int row = nt * 16 + rm;
        #pragma unroll
        for (int mt = 0; mt < 2; ++mt) {
          int col0 = cb + mt * 16 + q * 4;
          int idx = sidx(row, col0);
          U2 old = *(const U2*)(&H[idx]);               // lane-owned slots (h', scaled)
          float h0 = stanh(lo_bf(old.x) + a2[mt][0] + bb[mt][0]);
          float h1 = stanh(hi_bf(old.x) + a2[mt][1] + bb[mt][1]);
          float h2 = stanh(lo_bf(old.y) + a2[mt][2] + bb[mt][2]);
          float h3 = stanh(hi_bf(old.y) + a2[mt][3] + bb[mt][3]);
          U2 p; p.x = cvt_pk(h0, h1); p.y = cvt_pk(h2, h3);
          *(U2*)(&H[idx]) = p;
        }
      });
    }
    __syncthreads();
  }

  // ---- final: out = Waug @ [h'; state]^T + baug  (Waug h-half pre-divided by SCLF)
  // restage state -> G (G dead since last GEMM2; H-readers unaffected)
  #pragma unroll 2
  for (int qd = tid; qd < MTILE * (K0PAD / 4); qd += NTHR) {
    int m  = qd / (K0PAD / 4);
    int k0 = (qd - m * (K0PAD / 4)) * 4;
    const float* sp = state + (size_t)(row0 + m) * SDIM + k0;
    float f0 = (k0     < SDIM) ? sp[0] : 0.f;
    float f1 = (k0 + 1 < SDIM) ? sp[1] : 0.f;
    float f2 = (k0 + 2 < SDIM) ? sp[2] : 0.f;
    float f3 = (k0 + 3 < SDIM) ? sp[3] : 0.f;
    U2 p; p.x = cvt_pk(f0, f1); p.y = cvt_pk(f2, f3);
    *(U2*)(&G[sidx(m, k0)]) = p;
  }

  float4_ acc[2][NROWT];
  #pragma unroll
  for (int mt = 0; mt < 2; ++mt)
    #pragma unroll
    for (int nt = 0; nt < NROWT; ++nt) acc[mt][nt] = (float4_){0.f, 0.f, 0.f, 0.f};
  if (cb < 160)
    mma_wact<8, KAUG, 0>(H, Waug, acc, lane, cb);        // h' part (k 0..255)
  __syncthreads();                                       // G staged + H reads done
  if (cb < 160)
    mma_wact<5, KAUG, 256>(G, Waug, acc, lane, cb);      // state part (k 256..415)
  __syncthreads();                                       // all arena reads done
  if (cb < 160) {
    #pragma unroll
    for (int mt = 0; mt < 2; ++mt) {
      int col0 = cb + mt * 16 + q * 4;
      if (col0 <= 136) {
        float4_ bias = *(const float4_*)(baug + col0);
        #pragma unroll
        for (int nt = 0; nt < NROWT; ++nt) {
          int row = nt * 16 + rm;
          float4_ v;
          v[0] = acc[mt][nt][0] + bias[0];
          v[1] = acc[mt][nt][1] + bias[1];
          v[2] = acc[mt][nt][2] + bias[2];
          v[3] = acc[mt][nt][3] + bias[3];
          *(float4_*)(T + row * 140 + col0) = v;        // fp32 tile, stride 140
        }
      }
    }
  }
  __syncthreads();

  // ---- fully coalesced linear store: 128*137 contiguous floats (no div in loop)
  float* obase = out + (size_t)row0 * SDIM;
  int r = tid / SDIM;                 // 0..3
  int c = tid - r * SDIM;
  #pragma unroll 1
  for (int idx = tid; idx < MTILE * SDIM; idx += NTHR) {
    obase[idx] = T[r * 140 + c];
    c += NTHR - 3 * SDIM;             // +101  (512 = 3*137 + 101)
    r += 3;
    if (c >= SDIM) { c -= SDIM; r += 1; }
  }
}

extern "C" void kernel_launch(void* const* d_in, const int* in_sizes, int n_in,
                              void* d_out, int out_size, void* d_ws, size_t ws_size,
                              hipStream_t stream) {
  const float* t        = (const float*)d_in[0];
  const float* state    = (const float*)d_in[1];
  const float* W0       = (const float*)d_in[2];
  const float* b0       = (const float*)d_in[3];
  const float* blkW1    = (const float*)d_in[4];
  const float* blkb1    = (const float*)d_in[5];
  const float* blkW2    = (const float*)d_in[6];
  const float* blkb2    = (const float*)d_in[7];
  const float* Wout     = (const float*)d_in[8];
  const float* bout     = (const float*)d_in[9];
  const float* lm_in_w  = (const float*)d_in[10];
  const float* lm_in_b  = (const float*)d_in[11];
  const float* lm_out_w = (const float*)d_in[12];
  const float* lm_out_b = (const float*)d_in[13];
  const float* ta_in_w  = (const float*)d_in[14];
  const float* ta_in_b  = (const float*)d_in[15];
  const float* ta_out_w = (const float*)d_in[16];
  const float* ta_out_b = (const float*)d_in[17];

  char* ws = (char*)d_ws;
  unsigned short* W0p   = (unsigned short*)ws;                   // 256*160*2   = 81920
  float*          b0p   = (float*)(ws + 81920);                  // 1024
  unsigned short* Waug  = (unsigned short*)(ws + 82944);         // 256*416*2   = 212992
  float*          baug  = (float*)(ws + 295936);                 // 1024
  unsigned short* W1b   = (unsigned short*)(ws + 296960);        // 4*256*256*2 = 524288
  unsigned short* W2b   = (unsigned short*)(ws + 821248);        // 524288  (total ~1.31 MB)

  prep_w0<<<256, 64, 0, stream>>>(t, W0, b0, W0p, b0p);
  prep_fill<<<256, 128, 0, stream>>>(Wout, bout, Waug, baug);
  prep_ta<<<129, 128, 0, stream>>>(ta_in_w, ta_in_b, ta_out_w, ta_out_b,
                                   lm_in_w, lm_in_b, lm_out_w, lm_out_b, Waug, baug);
  prep_blk2<<<512, 256, 0, stream>>>(blkW1, blkW2, W1b, W2b);

  int batch = in_sizes[1] / SDIM;               // 131072
  fused_odefunc<<<batch / MTILE, NTHR, 0, stream>>>(
      state, W0p, b0p, W1b, blkb1, W2b, blkb2, Waug, baug,
      (float*)d_out);
}